// Round 6
// baseline (312.470 us; speedup 1.0000x reference)
//
#include <hip/hip_runtime.h>
#include <stdint.h>

#define B_ 32
#define T_ 4096
#define D_ 512
#define BT_ (B_*T_)

typedef __attribute__((ext_vector_type(8))) short bf16x8;
typedef __attribute__((ext_vector_type(4))) float f32x4;

__device__ __forceinline__ unsigned short f2bf(float f) {
    unsigned int u = __float_as_uint(f);
    u += 0x7FFFu + ((u >> 16) & 1u);   // round-to-nearest-even (inputs are finite)
    return (unsigned short)(u >> 16);
}

__device__ __forceinline__ float tanh_fast(float x) {
    float e2 = __expf(2.0f * x);       // inf for large x, 0 for very negative -> correct limits
    return 1.0f - 2.0f / (e2 + 1.0f);
}

// ---------------------------------------------------------------------------
// W_h (D x D fp32, [k][n]) -> bf16 MFMA B-fragment layout in ws:
//   wsb[((nt*16+kt)*64 + l)*8 + j] = bf16(W_h[kt*32 + (l>>4)*8 + j][nt*16 + (l&15)])
__global__ __launch_bounds__(256) void k_conv_wh(const float* __restrict__ W_h,
                                                 unsigned short* __restrict__ wsb) {
    int tid = blockIdx.x * 256 + threadIdx.x;   // 0..32767
    int l  = tid & 63;
    int kt = (tid >> 6) & 15;
    int nt = tid >> 10;
    int n  = nt * 16 + (l & 15);
    int k0 = kt * 32 + (l >> 4) * 8;
    unsigned int w[4];
#pragma unroll
    for (int q = 0; q < 4; ++q) {
        unsigned short lo = f2bf(W_h[(size_t)(k0 + 2*q)     * D_ + n]);
        unsigned short hi = f2bf(W_h[(size_t)(k0 + 2*q + 1) * D_ + n]);
        w[q] = (unsigned int)lo | ((unsigned int)hi << 16);
    }
    uint4 pk = {w[0], w[1], w[2], w[3]};
    ((uint4*)wsb)[tid] = pk;
}

// ---------------------------------------------------------------------------
// dec[b][c] = b_s[c] + sum_k s_t[b][k] * W_s[k][c]
__global__ __launch_bounds__(256) void k_dec(const float* __restrict__ s_t,
                                             const float* __restrict__ W_s,
                                             const float* __restrict__ b_s,
                                             float* __restrict__ dec) {
    int b = blockIdx.x;
    int c = threadIdx.x;
    float a0 = b_s[c], a1 = b_s[c + 256];
    const float* srow = s_t + b * D_;
    for (int k = 0; k < D_; ++k) {
        float s = srow[k];
        const float* wr = W_s + (size_t)k * D_;
        a0 = fmaf(s, wr[c], a0);
        a1 = fmaf(s, wr[c + 256], a1);
    }
    dec[b * D_ + c] = a0;
    dec[b * D_ + c + 256] = a1;
}

// ---------------------------------------------------------------------------
// Main fused kernel. Block = 64 rows of (B*T), 8 waves (512 threads).
// K split into 8 phases of 64. Phase pipeline (raw barriers, NO vmcnt drain):
//   phase j: [issue h_i loads for phase j+2 -> L[j&1]]
//            [MFMA kt=2j,2j+1 from panel slot j  + B-frag reload 1 phase ahead]
//            [convert L[(j+1)&1] -> panel slot j+1]  (compiler-counted vmcnt)
//            [lgkmcnt(0); s_barrier]
// Panel is single-buffered (each slot written once, read next phase) and stays
// fully resident for the fused context GEMV at the end.
// Register budget (spill-proof): acc 64 AGPR + L 16 + bq 32 + addr ~12 <= 128.
__global__ __launch_bounds__(512, 4) void k_main(const float* __restrict__ h_i,
                                                 const float* __restrict__ coverage,
                                                 const unsigned short* __restrict__ wsb,
                                                 const float* __restrict__ dec,
                                                 const float* __restrict__ W_c,
                                                 const float* __restrict__ V,
                                                 float* __restrict__ e_out,
                                                 float* __restrict__ part) {
    __shared__ __align__(16) unsigned char As[65536];
    __shared__ float red[8][64];
    __shared__ float wexp[64];
    const int tid = threadIdx.x;
    const int w = tid >> 6, l = tid & 63;
    const int row0 = blockIdx.x * 64;           // flat (b*T + t), 64-aligned
    const int b    = row0 >> 12;
    const int t0   = row0 & (T_ - 1);

    // ---- staging-side thread mapping: thread -> (row, 8-k-chunk) per phase
    const int srow = tid >> 3;                  // 0..63
    const int t8   = tid & 7;                   // 8-float chunk within 64-k phase
    const int ktb  = (t8 >> 2) & 1;             // kt low bit
    const int m    = t8 & 3;                    // lam>>4
    const int lamf = (srow & 15) + 16 * m;
    const int slot = (lamf & 0x38) | ((lamf & 7) ^ (m << 1) ^ ktb);
    const int sbyte0 = ((((srow >> 4) * 16) + ktb) << 10) | (slot << 4);
    const float* gsrc = h_i + (size_t)(row0 + srow) * D_ + t8 * 8;

    float4 L[2][2];
#pragma unroll
    for (int p = 0; p < 2; ++p) {
        L[p][0] = *(const float4*)(gsrc + p * 64);
        L[p][1] = *(const float4*)(gsrc + p * 64 + 4);
    }
    // convert phase 0 into panel
    {
        uint4 pk;
        pk.x = (unsigned)f2bf(L[0][0].x) | ((unsigned)f2bf(L[0][0].y) << 16);
        pk.y = (unsigned)f2bf(L[0][0].z) | ((unsigned)f2bf(L[0][0].w) << 16);
        pk.z = (unsigned)f2bf(L[0][1].x) | ((unsigned)f2bf(L[0][1].y) << 16);
        pk.w = (unsigned)f2bf(L[0][1].z) | ((unsigned)f2bf(L[0][1].w) << 16);
        *(uint4*)(As + sbyte0) = pk;
    }
    asm volatile("s_waitcnt lgkmcnt(0)" ::: "memory");
    __builtin_amdgcn_s_barrier();

    // ---- compute-side invariants
    const int slotR = (l & 0x38) | ((l & 7) ^ (((l >> 4) & 3) << 1));
    const uint4* bw = (const uint4*)wsb + ((w * 4) << 10) + l;   // + jj*1024 + kt*64

    f32x4 acc[4][4];                            // [af][jj]
#pragma unroll
    for (int af = 0; af < 4; ++af)
#pragma unroll
        for (int jj = 0; jj < 4; ++jj) acc[af][jj] = (f32x4){0, 0, 0, 0};

    uint4 bq0[4], bq1[4];                       // B frags for kt=2j / 2j+1
#pragma unroll
    for (int jj = 0; jj < 4; ++jj) bq0[jj] = bw[(jj << 10)];
#pragma unroll
    for (int jj = 0; jj < 4; ++jj) bq1[jj] = bw[(jj << 10) + (1 << 6)];

#pragma unroll
    for (int j = 0; j < 8; ++j) {
        // (1) issue phase j+2 loads into the buffer freed by last phase's convert
        if (j + 2 < 8) {
            L[j & 1][0] = *(const float4*)(gsrc + (j + 2) * 64);
            L[j & 1][1] = *(const float4*)(gsrc + (j + 2) * 64 + 4);
        }
        __builtin_amdgcn_sched_barrier(0);

        // (2) compute kt=2j, then kt=2j+1; reload B frags one phase ahead
        {
            const int kt = 2 * j;
            const int sl = (slotR ^ (kt & 1)) << 4;
#pragma unroll
            for (int af = 0; af < 4; ++af) {
                uint4 araw = *(const uint4*)(As + ((af * 16 + kt) << 10) + sl);
                bf16x8 a = __builtin_bit_cast(bf16x8, araw);
#pragma unroll
                for (int jj = 0; jj < 4; ++jj) {
                    bf16x8 bv = __builtin_bit_cast(bf16x8, bq0[jj]);
                    acc[af][jj] = __builtin_amdgcn_mfma_f32_16x16x32_bf16(a, bv, acc[af][jj], 0, 0, 0);
                }
            }
            if (j < 7) {
#pragma unroll
                for (int jj = 0; jj < 4; ++jj) bq0[jj] = bw[(jj << 10) + ((2 * j + 2) << 6)];
            }
        }
        {
            const int kt = 2 * j + 1;
            const int sl = (slotR ^ (kt & 1)) << 4;
#pragma unroll
            for (int af = 0; af < 4; ++af) {
                uint4 araw = *(const uint4*)(As + ((af * 16 + kt) << 10) + sl);
                bf16x8 a = __builtin_bit_cast(bf16x8, araw);
#pragma unroll
                for (int jj = 0; jj < 4; ++jj) {
                    bf16x8 bv = __builtin_bit_cast(bf16x8, bq1[jj]);
                    acc[af][jj] = __builtin_amdgcn_mfma_f32_16x16x32_bf16(a, bv, acc[af][jj], 0, 0, 0);
                }
            }
            if (j < 7) {
#pragma unroll
                for (int jj = 0; jj < 4; ++jj) bq1[jj] = bw[(jj << 10) + ((2 * j + 3) << 6)];
            }
        }
        __builtin_amdgcn_sched_barrier(0);

        // (3) convert phase j+1 into its panel slot (waits only its own vmcnt)
        if (j + 1 < 8) {
            float4* Lp = L[(j + 1) & 1];
            uint4 pk;
            pk.x = (unsigned)f2bf(Lp[0].x) | ((unsigned)f2bf(Lp[0].y) << 16);
            pk.y = (unsigned)f2bf(Lp[0].z) | ((unsigned)f2bf(Lp[0].w) << 16);
            pk.z = (unsigned)f2bf(Lp[1].x) | ((unsigned)f2bf(Lp[1].y) << 16);
            pk.w = (unsigned)f2bf(Lp[1].z) | ((unsigned)f2bf(Lp[1].w) << 16);
            *(uint4*)(As + sbyte0 + ((2 * (j + 1)) << 10)) = pk;
        }
        // (4) LDS writes visible to all waves; loads-to-regs stay in flight
        if (j < 7) {
            asm volatile("s_waitcnt lgkmcnt(0)" ::: "memory");
            __builtin_amdgcn_s_barrier();
        }
    }

    // ---- epilogue: tanh + dot with V over this wave's 64 cols
    const int rgrp = (l >> 4) * 4;
    float cov_r[4][4];
#pragma unroll
    for (int af = 0; af < 4; ++af)
#pragma unroll
        for (int r = 0; r < 4; ++r)
            cov_r[af][r] = coverage[b * T_ + t0 + af * 16 + rgrp + r];

    float p[4][4] = {{0,0,0,0},{0,0,0,0},{0,0,0,0},{0,0,0,0}};  // [af][r]
#pragma unroll
    for (int jj = 0; jj < 4; ++jj) {
        int col = w * 64 + jj * 16 + (l & 15);
        float dv = dec[b * D_ + col];
        float wc = W_c[col];
        float vv = V[col];
#pragma unroll
        for (int af = 0; af < 4; ++af)
#pragma unroll
            for (int r = 0; r < 4; ++r) {
                float x = acc[af][jj][r] + dv + cov_r[af][r] * wc;
                p[af][r] += tanh_fast(x) * vv;
            }
    }

    // reduce across the 16 lanes sharing each row (lane bits 0..3)
#pragma unroll
    for (int mm = 1; mm <= 8; mm <<= 1)
#pragma unroll
        for (int af = 0; af < 4; ++af)
#pragma unroll
            for (int r = 0; r < 4; ++r)
                p[af][r] += __shfl_xor(p[af][r], mm, 64);
    if ((l & 15) == 0) {
#pragma unroll
        for (int af = 0; af < 4; ++af)
#pragma unroll
            for (int r = 0; r < 4; ++r)
                red[w][af * 16 + rgrp + r] = p[af][r];
    }
    __syncthreads();
    if (tid < 64) {
        float e = red[0][tid] + red[1][tid] + red[2][tid] + red[3][tid]
                + red[4][tid] + red[5][tid] + red[6][tid] + red[7][tid];
        e_out[b * T_ + t0 + tid] = e;
        wexp[tid] = __expf(e);
    }
    __syncthreads();

    // ---- fused context partial: part[blk][d] = sum_t wexp[t] * A[t][d]
    {
        const int d    = tid;
        const int ktg  = d >> 5;
        const int mq   = (d >> 3) & 3;
        const int base2 = ((mq << 4) | (((mq << 1) ^ (ktg & 1)) & 7)) << 4;
        const unsigned char* Ag = As + (ktg << 10) + ((d & 7) << 1);
        float cacc = 0.f;
#pragma unroll
        for (int t = 0; t < 64; ++t) {
            int byte = ((t >> 4) << 14) + (base2 ^ ((t & 15) << 4));
            unsigned short u = *(const unsigned short*)(Ag + byte);
            float hv = __uint_as_float(((unsigned)u) << 16);
            cacc = fmaf(wexp[t], hv, cacc);
        }
        part[(size_t)blockIdx.x * D_ + d] = cacc;
    }
}

// ---------------------------------------------------------------------------
// Softmax over T per batch + new_coverage; also emits S_b = exp(m)*Z for the
// fused context normalization.
__global__ __launch_bounds__(256) void k_soft(const float* __restrict__ e_in,
                                              const float* __restrict__ coverage,
                                              float* __restrict__ out_at,
                                              float* __restrict__ out_cov,
                                              float* __restrict__ Sb) {
    int b = blockIdx.x, tid = threadIdx.x;
    __shared__ float red[4];
    float v[16];
    float m = -1e30f;
#pragma unroll
    for (int i = 0; i < 16; ++i) {
        v[i] = e_in[b * T_ + tid + i * 256];
        m = fmaxf(m, v[i]);
    }
#pragma unroll
    for (int mk = 1; mk <= 32; mk <<= 1) m = fmaxf(m, __shfl_xor(m, mk, 64));
    if ((tid & 63) == 0) red[tid >> 6] = m;
    __syncthreads();
    m = fmaxf(fmaxf(red[0], red[1]), fmaxf(red[2], red[3]));
    float s = 0.f;
#pragma unroll
    for (int i = 0; i < 16; ++i) { v[i] = expf(v[i] - m); s += v[i]; }
#pragma unroll
    for (int mk = 1; mk <= 32; mk <<= 1) s += __shfl_xor(s, mk, 64);
    __syncthreads();
    if ((tid & 63) == 0) red[tid >> 6] = s;
    __syncthreads();
    s = red[0] + red[1] + red[2] + red[3];
    if (tid == 0) Sb[b] = __expf(m) * s;       // sum_t exp(e_t), stable form
    float inv = 1.0f / s;
#pragma unroll
    for (int i = 0; i < 16; ++i) {
        int idx = b * T_ + tid + i * 256;
        float a = v[i] * inv;
        out_at[idx]  = a;
        out_cov[idx] = coverage[idx] + a;
    }
}

// ---------------------------------------------------------------------------
// combine: context[b][d] = (sum_s part[(b*64+s)][d]) / S_b   (deterministic)
__global__ __launch_bounds__(256) void k_comb(const float* __restrict__ part,
                                              const float* __restrict__ Sb,
                                              float* __restrict__ out_ctx) {
    int idx = blockIdx.x * 256 + threadIdx.x;   // 0..16383
    int b = idx >> 9, d = idx & 511;
    const float* pp = part + (size_t)b * 64 * D_ + d;
    float s = 0.f;
#pragma unroll 8
    for (int j = 0; j < 64; ++j) s += pp[(size_t)j * D_];
    out_ctx[idx] = s / Sb[b];
}

// ---------------------------------------------------------------------------
extern "C" void kernel_launch(void* const* d_in, const int* in_sizes, int n_in,
                              void* d_out, int out_size, void* d_ws, size_t ws_size,
                              hipStream_t stream) {
    const float* h_i      = (const float*)d_in[0];
    const float* s_t      = (const float*)d_in[1];
    const float* coverage = (const float*)d_in[2];
    const float* W_h      = (const float*)d_in[3];
    const float* W_s      = (const float*)d_in[4];
    const float* b_s      = (const float*)d_in[5];
    const float* W_c      = (const float*)d_in[6];
    const float* V        = (const float*)d_in[7];

    float* out_ctx = (float*)d_out;             // B*D
    float* out_at  = out_ctx + B_ * D_;         // B*T (holds e_t between k_main and k_soft)
    float* out_cov = out_at + BT_;              // B*T

    unsigned short* wsb = (unsigned short*)d_ws;              // 512 KB bf16 W_h frags
    float* dec  = (float*)((char*)d_ws + 524288);             // 64 KB
    float* part = dec + B_ * D_;                              // 4 MB (2048 x 512)
    float* Sb   = part + (size_t)BT_ / 64 * D_;               // 32 floats

    k_conv_wh<<<128, 256, 0, stream>>>(W_h, wsb);
    k_dec<<<B_, 256, 0, stream>>>(s_t, W_s, b_s, dec);
    k_main<<<BT_ / 64, 512, 0, stream>>>(h_i, coverage, wsb, dec, W_c, V, out_at, part);
    k_soft<<<B_, 256, 0, stream>>>(out_at, coverage, out_at, out_cov, Sb);
    k_comb<<<B_ * D_ / 256, 256, 0, stream>>>(part, Sb, out_ctx);
}

// Round 9
// 237.158 us; speedup vs baseline: 1.3176x; 1.3176x over previous
//
#include <hip/hip_runtime.h>
#include <stdint.h>

#define B_ 32
#define T_ 4096
#define D_ 512
#define BT_ (B_*T_)

typedef __attribute__((ext_vector_type(8))) short bf16x8;
typedef __attribute__((ext_vector_type(4))) float f32x4;

__device__ __forceinline__ unsigned short f2bf(float f) {
    unsigned int u = __float_as_uint(f);
    u += 0x7FFFu + ((u >> 16) & 1u);   // round-to-nearest-even (inputs are finite)
    return (unsigned short)(u >> 16);
}

__device__ __forceinline__ unsigned pk2(float a, float b) {
    return (unsigned)f2bf(a) | ((unsigned)f2bf(b) << 16);   // low16 = a, high16 = b
}

__device__ __forceinline__ float tanh_fast(float x) {
    float e2 = __expf(2.0f * x);
    return 1.0f - 2.0f / (e2 + 1.0f);
}

// async global->LDS DMA, 16B per lane. LDS dest = wave-uniform base + lane*16;
// global src = per-lane address. offset arg always 0 (all offsets pre-folded
// into the pointers to avoid any ambiguity in the builtin's offset semantics).
__device__ __forceinline__ void gl16(const float* g, const float* lds) {
    __builtin_amdgcn_global_load_lds(
        (const __attribute__((address_space(1))) void*)g,
        (__attribute__((address_space(3))) void*)lds, 16, 0, 0);
}

#define WAITVM(N) asm volatile("s_waitcnt vmcnt(" #N ")" ::: "memory")

// ---------------------------------------------------------------------------
// W_h (D x D fp32, [k][n]) -> bf16 MFMA B-fragment layout in ws (unchanged).
__global__ __launch_bounds__(256) void k_conv_wh(const float* __restrict__ W_h,
                                                 unsigned short* __restrict__ wsb) {
    int tid = blockIdx.x * 256 + threadIdx.x;
    int l  = tid & 63;
    int kt = (tid >> 6) & 15;
    int nt = tid >> 10;
    int n  = nt * 16 + (l & 15);
    int k0 = kt * 32 + (l >> 4) * 8;
    unsigned int w[4];
#pragma unroll
    for (int q = 0; q < 4; ++q) {
        unsigned short lo = f2bf(W_h[(size_t)(k0 + 2*q)     * D_ + n]);
        unsigned short hi = f2bf(W_h[(size_t)(k0 + 2*q + 1) * D_ + n]);
        w[q] = (unsigned int)lo | ((unsigned int)hi << 16);
    }
    uint4 pk = {w[0], w[1], w[2], w[3]};
    ((uint4*)wsb)[tid] = pk;
}

// ---------------------------------------------------------------------------
__global__ __launch_bounds__(256) void k_dec(const float* __restrict__ s_t,
                                             const float* __restrict__ W_s,
                                             const float* __restrict__ b_s,
                                             float* __restrict__ dec) {
    int b = blockIdx.x;
    int c = threadIdx.x;
    float a0 = b_s[c], a1 = b_s[c + 256];
    const float* srow = s_t + b * D_;
    for (int k = 0; k < D_; ++k) {
        float s = srow[k];
        const float* wr = W_s + (size_t)k * D_;
        a0 = fmaf(s, wr[c], a0);
        a1 = fmaf(s, wr[c + 256], a1);
    }
    dec[b * D_ + c] = a0;
    dec[b * D_ + c + 256] = a1;
}

// ---------------------------------------------------------------------------
// Main fused kernel. Block = 64 rows, 8 waves, 1 block/CU (131KB LDS).
// fp32 panel, frag-blocked: frag f=(af*16+kt) is floats [f*512, f*512+512):
//   lo half: lane*4 floats (j0-3), hi half: 256 + lane*4 (j4-7),
//   lane slot holds h[row0+af*16+(l&15)][kt*32+(l>>4)*8 + j].
// Staged by global_load_lds (no VGPRs), quarter-pipelined with counted vmcnt.
// Wave w computes cols [w*64, w*64+64); epilogue fuses tanh/V-dot and the
// context partial (fp32 panel re-read, conflict-free frag pattern + shfl).
__global__ __launch_bounds__(512, 2) void k_main(const float* __restrict__ h_i,
                                                 const float* __restrict__ coverage,
                                                 const unsigned short* __restrict__ wsb,
                                                 const float* __restrict__ dec,
                                                 const float* __restrict__ W_c,
                                                 const float* __restrict__ V,
                                                 float* __restrict__ e_out,
                                                 float* __restrict__ part) {
    __shared__ __align__(16) float As[64 * 512];   // 131072 B
    __shared__ float red[8][64];
    __shared__ float wexp[64];
    const int tid = threadIdx.x;
    const int w = tid >> 6, l = tid & 63;
    const int row0 = blockIdx.x * 64;
    const int b    = row0 >> 12;
    const int t0   = row0 & (T_ - 1);

    // staging: wave w covers af = w>>1, kt pair base (w&1)*2 per quarter.
    const float* gp = h_i + (size_t)(row0 + (w >> 1) * 16 + (l & 15)) * D_
                          + ((l >> 4) * 8) + (w & 1) * 64;
    const float* lb = As + ((w >> 1) * 16 + (w & 1) * 2) * 512;

    // offsets folded into pointers; builtin offset arg = 0 always.
#define STG(Q, II) gl16(gp + ((Q)*128 + ((II)>>1)*32 + ((II)&1)*4), \
                        lb + ((Q)*4 + ((II)>>1))*512 + ((II)&1)*256)

    // prologue: quarters 0..2 in flight (12 instrs/wave)
    STG(0,0); STG(0,1); STG(0,2); STG(0,3);
    STG(1,0); STG(1,1); STG(1,2); STG(1,3);
    STG(2,0); STG(2,1); STG(2,2); STG(2,3);

    const int rgrp = (l >> 4) * 4;
    const uint4* bw = (const uint4*)wsb + ((w * 4) << 10) + l;

    f32x4 acc[4][4];
#pragma unroll
    for (int af = 0; af < 4; ++af)
#pragma unroll
        for (int jj = 0; jj < 4; ++jj) acc[af][jj] = (f32x4){0, 0, 0, 0};

#define QMM(Q)                                                                \
    _Pragma("unroll")                                                         \
    for (int ktl = 0; ktl < 4; ++ktl) {                                       \
        _Pragma("unroll")                                                     \
        for (int af = 0; af < 4; ++af) {                                      \
            const float* fr = As + (af * 16 + (Q) * 4 + ktl) * 512 + l * 4;   \
            float4 lo = *(const float4*)fr;                                   \
            float4 hi = *(const float4*)(fr + 256);                           \
            uint4 a4 = {pk2(lo.x, lo.y), pk2(lo.z, lo.w),                     \
                        pk2(hi.x, hi.y), pk2(hi.z, hi.w)};                    \
            bf16x8 a = __builtin_bit_cast(bf16x8, a4);                        \
            _Pragma("unroll")                                                 \
            for (int jj = 0; jj < 4; ++jj)                                    \
                acc[af][jj] = __builtin_amdgcn_mfma_f32_16x16x32_bf16(        \
                    a, __builtin_bit_cast(bf16x8, bq[ktl][jj]),               \
                    acc[af][jj], 0, 0, 0);                                    \
        }                                                                     \
    }

#define BLOADS(Q)                                                             \
    _Pragma("unroll")                                                         \
    for (int ktl = 0; ktl < 4; ++ktl)                                         \
        _Pragma("unroll")                                                     \
        for (int jj = 0; jj < 4; ++jj)                                        \
            bq[ktl][jj] = bw[(jj << 10) + (((Q) * 4 + ktl) << 6)];

    // ---- quarter 0: wait own q0 staging (12 out -> 8), B first, then q3a
    WAITVM(8);
    __builtin_amdgcn_s_barrier();
    __builtin_amdgcn_sched_barrier(0);
    {
        uint4 bq[4][4];
        BLOADS(0);
        __builtin_amdgcn_sched_barrier(0);
        STG(3,0); STG(3,1);
        __builtin_amdgcn_sched_barrier(0);
        QMM(0);
    }
    // ---- quarter 1
    WAITVM(6);
    __builtin_amdgcn_s_barrier();
    __builtin_amdgcn_sched_barrier(0);
    {
        uint4 bq[4][4];
        BLOADS(1);
        __builtin_amdgcn_sched_barrier(0);
        STG(3,2); STG(3,3);
        __builtin_amdgcn_sched_barrier(0);
        QMM(1);
    }
    // ---- quarter 2
    WAITVM(4);
    __builtin_amdgcn_s_barrier();
    __builtin_amdgcn_sched_barrier(0);
    {
        uint4 bq[4][4];
        BLOADS(2);
        __builtin_amdgcn_sched_barrier(0);
        QMM(2);
    }
    // ---- quarter 3 (drain)
    WAITVM(0);
    __builtin_amdgcn_s_barrier();
    __builtin_amdgcn_sched_barrier(0);
    {
        uint4 bq[4][4];
        BLOADS(3);
        __builtin_amdgcn_sched_barrier(0);
        QMM(3);
    }

    // ---- epilogue: tanh + dot with V over this wave's 64 cols
    float cov_r[4][4];
#pragma unroll
    for (int af = 0; af < 4; ++af)
#pragma unroll
        for (int r = 0; r < 4; ++r)
            cov_r[af][r] = coverage[b * T_ + t0 + af * 16 + rgrp + r];

    float p[4][4] = {{0,0,0,0},{0,0,0,0},{0,0,0,0},{0,0,0,0}};
#pragma unroll
    for (int jj = 0; jj < 4; ++jj) {
        int col = w * 64 + jj * 16 + (l & 15);
        float dv = dec[b * D_ + col];
        float wc = W_c[col];
        float vv = V[col];
#pragma unroll
        for (int af = 0; af < 4; ++af)
#pragma unroll
            for (int r = 0; r < 4; ++r) {
                float x = acc[af][jj][r] + dv + cov_r[af][r] * wc;
                p[af][r] += tanh_fast(x) * vv;
            }
    }

#pragma unroll
    for (int mm = 1; mm <= 8; mm <<= 1)
#pragma unroll
        for (int af = 0; af < 4; ++af)
#pragma unroll
            for (int r = 0; r < 4; ++r)
                p[af][r] += __shfl_xor(p[af][r], mm, 64);
    if ((l & 15) == 0) {
#pragma unroll
        for (int af = 0; af < 4; ++af)
#pragma unroll
            for (int r = 0; r < 4; ++r)
                red[w][af * 16 + rgrp + r] = p[af][r];
    }
    __syncthreads();
    if (tid < 64) {
        float e = red[0][tid] + red[1][tid] + red[2][tid] + red[3][tid]
                + red[4][tid] + red[5][tid] + red[6][tid] + red[7][tid];
        e_out[b * T_ + t0 + tid] = e;
        wexp[tid] = __expf(e);
    }
    __syncthreads();

    // ---- fused context partial from the fp32 panel.
    // Wave w handles kt = 2w, 2w+1; lane l accumulates rows af*16+(l&15)
    // for k = kt*32 + (l>>4)*8 + j, then reduces over the 16 row-lanes.
    {
        float pc[2][8] = {{0,0,0,0,0,0,0,0},{0,0,0,0,0,0,0,0}};
#pragma unroll
        for (int ktq = 0; ktq < 2; ++ktq) {
            const int kt = w * 2 + ktq;
#pragma unroll
            for (int af = 0; af < 4; ++af) {
                float wv = wexp[af * 16 + (l & 15)];
                const float* fr = As + (af * 16 + kt) * 512 + l * 4;
                float4 lo = *(const float4*)fr;
                float4 hi = *(const float4*)(fr + 256);
                pc[ktq][0] = fmaf(wv, lo.x, pc[ktq][0]);
                pc[ktq][1] = fmaf(wv, lo.y, pc[ktq][1]);
                pc[ktq][2] = fmaf(wv, lo.z, pc[ktq][2]);
                pc[ktq][3] = fmaf(wv, lo.w, pc[ktq][3]);
                pc[ktq][4] = fmaf(wv, hi.x, pc[ktq][4]);
                pc[ktq][5] = fmaf(wv, hi.y, pc[ktq][5]);
                pc[ktq][6] = fmaf(wv, hi.z, pc[ktq][6]);
                pc[ktq][7] = fmaf(wv, hi.w, pc[ktq][7]);
            }
        }
#pragma unroll
        for (int mm = 1; mm <= 8; mm <<= 1)
#pragma unroll
            for (int ktq = 0; ktq < 2; ++ktq)
#pragma unroll
                for (int j = 0; j < 8; ++j)
                    pc[ktq][j] += __shfl_xor(pc[ktq][j], mm, 64);
        if ((l & 15) == 0) {
#pragma unroll
            for (int ktq = 0; ktq < 2; ++ktq) {
                float* dst = part + (size_t)blockIdx.x * D_
                           + (w * 2 + ktq) * 32 + (l >> 4) * 8;
                *(float4*)dst       = float4{pc[ktq][0], pc[ktq][1], pc[ktq][2], pc[ktq][3]};
                *(float4*)(dst + 4) = float4{pc[ktq][4], pc[ktq][5], pc[ktq][6], pc[ktq][7]};
            }
        }
    }
}

// ---------------------------------------------------------------------------
__global__ __launch_bounds__(256) void k_soft(const float* __restrict__ e_in,
                                              const float* __restrict__ coverage,
                                              float* __restrict__ out_at,
                                              float* __restrict__ out_cov,
                                              float* __restrict__ Sb) {
    int b = blockIdx.x, tid = threadIdx.x;
    __shared__ float red[4];
    float v[16];
    float m = -1e30f;
#pragma unroll
    for (int i = 0; i < 16; ++i) {
        v[i] = e_in[b * T_ + tid + i * 256];
        m = fmaxf(m, v[i]);
    }
#pragma unroll
    for (int mk = 1; mk <= 32; mk <<= 1) m = fmaxf(m, __shfl_xor(m, mk, 64));
    if ((tid & 63) == 0) red[tid >> 6] = m;
    __syncthreads();
    m = fmaxf(fmaxf(red[0], red[1]), fmaxf(red[2], red[3]));
    float s = 0.f;
#pragma unroll
    for (int i = 0; i < 16; ++i) { v[i] = expf(v[i] - m); s += v[i]; }
#pragma unroll
    for (int mk = 1; mk <= 32; mk <<= 1) s += __shfl_xor(s, mk, 64);
    __syncthreads();
    if ((tid & 63) == 0) red[tid >> 6] = s;
    __syncthreads();
    s = red[0] + red[1] + red[2] + red[3];
    if (tid == 0) Sb[b] = __expf(m) * s;
    float inv = 1.0f / s;
#pragma unroll
    for (int i = 0; i < 16; ++i) {
        int idx = b * T_ + tid + i * 256;
        float a = v[i] * inv;
        out_at[idx]  = a;
        out_cov[idx] = coverage[idx] + a;
    }
}

// ---------------------------------------------------------------------------
__global__ __launch_bounds__(256) void k_comb(const float* __restrict__ part,
                                              const float* __restrict__ Sb,
                                              float* __restrict__ out_ctx) {
    int idx = blockIdx.x * 256 + threadIdx.x;
    int b = idx >> 9, d = idx & 511;
    const float* pp = part + (size_t)b * 64 * D_ + d;
    float s = 0.f;
#pragma unroll 8
    for (int j = 0; j < 64; ++j) s += pp[(size_t)j * D_];
    out_ctx[idx] = s / Sb[b];
}

// ---------------------------------------------------------------------------
extern "C" void kernel_launch(void* const* d_in, const int* in_sizes, int n_in,
                              void* d_out, int out_size, void* d_ws, size_t ws_size,
                              hipStream_t stream) {
    const float* h_i      = (const float*)d_in[0];
    const float* s_t      = (const float*)d_in[1];
    const float* coverage = (const float*)d_in[2];
    const float* W_h      = (const float*)d_in[3];
    const float* W_s      = (const float*)d_in[4];
    const float* b_s      = (const float*)d_in[5];
    const float* W_c      = (const float*)d_in[6];
    const float* V        = (const float*)d_in[7];

    float* out_ctx = (float*)d_out;             // B*D
    float* out_at  = out_ctx + B_ * D_;         // B*T (e_t between k_main and k_soft)
    float* out_cov = out_at + BT_;              // B*T

    unsigned short* wsb = (unsigned short*)d_ws;              // 512 KB bf16 W_h frags
    float* dec  = (float*)((char*)d_ws + 524288);             // 64 KB
    float* part = dec + B_ * D_;                              // 4 MB (2048 x 512)
    float* Sb   = part + (size_t)BT_ / 64 * D_;               // 32 floats

    k_conv_wh<<<128, 256, 0, stream>>>(W_h, wsb);
    k_dec<<<B_, 256, 0, stream>>>(s_t, W_s, b_s, dec);
    k_main<<<BT_ / 64, 512, 0, stream>>>(h_i, coverage, wsb, dec, W_c, V, out_at, part);
    k_soft<<<B_, 256, 0, stream>>>(out_at, coverage, out_at, out_cov, Sb);
    k_comb<<<B_ * D_ / 256, 256, 0, stream>>>(part, Sb, out_ctx);
}

// Round 10
// 212.642 us; speedup vs baseline: 1.4695x; 1.1153x over previous
//
#include <hip/hip_runtime.h>
#include <stdint.h>

#define B_ 32
#define T_ 4096
#define D_ 512
#define BT_ (B_*T_)

typedef __attribute__((ext_vector_type(8))) short bf16x8;
typedef __attribute__((ext_vector_type(4))) float f32x4;

__device__ __forceinline__ unsigned short f2bf(float f) {
    unsigned int u = __float_as_uint(f);
    u += 0x7FFFu + ((u >> 16) & 1u);   // round-to-nearest-even (inputs are finite)
    return (unsigned short)(u >> 16);
}

__device__ __forceinline__ unsigned pk2(float a, float b) {
    return (unsigned)f2bf(a) | ((unsigned)f2bf(b) << 16);   // low16 = a, high16 = b
}

__device__ __forceinline__ float tanh_fast(float x) {
    float e2 = __expf(2.0f * x);
    return 1.0f - 2.0f / (e2 + 1.0f);
}

// ---------------------------------------------------------------------------
// W_h (D x D fp32, [k][n]) -> bf16 MFMA B-fragment layout in ws (unchanged).
__global__ __launch_bounds__(256) void k_conv_wh(const float* __restrict__ W_h,
                                                 unsigned short* __restrict__ wsb) {
    int tid = blockIdx.x * 256 + threadIdx.x;
    int l  = tid & 63;
    int kt = (tid >> 6) & 15;
    int nt = tid >> 10;
    int n  = nt * 16 + (l & 15);
    int k0 = kt * 32 + (l >> 4) * 8;
    unsigned int w[4];
#pragma unroll
    for (int q = 0; q < 4; ++q) {
        unsigned short lo = f2bf(W_h[(size_t)(k0 + 2*q)     * D_ + n]);
        unsigned short hi = f2bf(W_h[(size_t)(k0 + 2*q + 1) * D_ + n]);
        w[q] = (unsigned int)lo | ((unsigned int)hi << 16);
    }
    uint4 pk = {w[0], w[1], w[2], w[3]};
    ((uint4*)wsb)[tid] = pk;
}

// ---------------------------------------------------------------------------
__global__ __launch_bounds__(256) void k_dec(const float* __restrict__ s_t,
                                             const float* __restrict__ W_s,
                                             const float* __restrict__ b_s,
                                             float* __restrict__ dec) {
    int b = blockIdx.x;
    int c = threadIdx.x;
    float a0 = b_s[c], a1 = b_s[c + 256];
    const float* srow = s_t + b * D_;
    for (int k = 0; k < D_; ++k) {
        float s = srow[k];
        const float* wr = W_s + (size_t)k * D_;
        a0 = fmaf(s, wr[c], a0);
        a1 = fmaf(s, wr[c + 256], a1);
    }
    dec[b * D_ + c] = a0;
    dec[b * D_ + c + 256] = a1;
}

// ---------------------------------------------------------------------------
// Main fused kernel. Block = 64 rows of (B*T), 16 waves (1024 threads),
// 2 blocks/CU (launch_bounds(1024,8) -> <=64 regs -> 8 waves/SIMD).
// bf16 panel (64 rows x 512 K) in LDS, sigma-swizzled frag layout,
// convert-on-WRITE (once per element). Wave w computes cols [w*32, w*32+32).
// Epilogue fuses tanh/V-dot; context partial from the bf16 panel (1 kt/wave).
__global__ __launch_bounds__(1024, 8) void k_main(const float* __restrict__ h_i,
                                                  const float* __restrict__ coverage,
                                                  const unsigned short* __restrict__ wsb,
                                                  const float* __restrict__ dec,
                                                  const float* __restrict__ W_c,
                                                  const float* __restrict__ V,
                                                  float* __restrict__ e_out,
                                                  float* __restrict__ part) {
    __shared__ __align__(16) unsigned char As[65536];
    __shared__ float red[16][64];
    __shared__ float wexp[64];
    const int tid = threadIdx.x;
    const int w = tid >> 6, l = tid & 63;      // w: 0..15
    const int row0 = blockIdx.x * 64;
    const int b    = row0 >> 12;
    const int t0   = row0 & (T_ - 1);

    // ---- stage A: wave w loads rows {0,16,32,48}+w; lane l its 8-float chunk.
    // frag slot (constant per thread): lamf = 16*(l&3) + w
    const int kt_s = l >> 2;
    const int lamf = ((l & 3) << 4) + w;
    const int slot = (lamf & 0x38) | ((lamf & 7) ^ (((l & 3) << 1)) ^ (kt_s & 1));
    const int sb0  = (kt_s << 10) + (slot << 4);
    const float* gsrc = h_i + (size_t)(row0 + w) * D_ + l * 8;

#pragma unroll
    for (int pass = 0; pass < 2; ++pass) {
        float4 Lf[2][2];
#pragma unroll
        for (int i = 0; i < 2; ++i) {
            const float* src = gsrc + (size_t)((pass * 2 + i) * 16) * D_;
            Lf[i][0] = *(const float4*)src;
            Lf[i][1] = *(const float4*)(src + 4);
        }
#pragma unroll
        for (int i = 0; i < 2; ++i) {
            uint4 pk;
            pk.x = pk2(Lf[i][0].x, Lf[i][0].y);
            pk.y = pk2(Lf[i][0].z, Lf[i][0].w);
            pk.z = pk2(Lf[i][1].x, Lf[i][1].y);
            pk.w = pk2(Lf[i][1].z, Lf[i][1].w);
            *(uint4*)(As + (((pass * 2 + i) * 16) << 10) + sb0) = pk;
        }
    }
    __syncthreads();

    // ---- K loop: wave w, cols nt = w*2 + {0,1}; 2-deep B prefetch
    const int slotR = (l & 0x38) | ((l & 7) ^ (((l >> 4) & 3) << 1));
    const uint4* bw = (const uint4*)wsb + ((w * 2) << 10) + l;

    f32x4 acc[4][2];
#pragma unroll
    for (int af = 0; af < 4; ++af) {
        acc[af][0] = (f32x4){0, 0, 0, 0};
        acc[af][1] = (f32x4){0, 0, 0, 0};
    }
    uint4 bp[2][2];
    bp[0][0] = bw[0];        bp[0][1] = bw[1 << 10];
    bp[1][0] = bw[1 << 6];   bp[1][1] = bw[(1 << 10) + (1 << 6)];

#pragma unroll
    for (int kt = 0; kt < 16; ++kt) {
        const int sl = (slotR ^ (kt & 1)) << 4;
#pragma unroll
        for (int af = 0; af < 4; ++af) {
            uint4 araw = *(const uint4*)(As + ((af * 16 + kt) << 10) + sl);
            bf16x8 a = __builtin_bit_cast(bf16x8, araw);
            acc[af][0] = __builtin_amdgcn_mfma_f32_16x16x32_bf16(
                a, __builtin_bit_cast(bf16x8, bp[kt & 1][0]), acc[af][0], 0, 0, 0);
            acc[af][1] = __builtin_amdgcn_mfma_f32_16x16x32_bf16(
                a, __builtin_bit_cast(bf16x8, bp[kt & 1][1]), acc[af][1], 0, 0, 0);
        }
        if (kt < 14) {
            bp[kt & 1][0] = bw[((kt + 2) << 6)];
            bp[kt & 1][1] = bw[(1 << 10) + ((kt + 2) << 6)];
        }
    }

    // ---- epilogue: tanh + dot with V over this wave's 32 cols
    const int rgrp = (l >> 4) * 4;
    float p[4][4] = {{0,0,0,0},{0,0,0,0},{0,0,0,0},{0,0,0,0}};
    {
        int col0 = w * 32 + (l & 15);
        float dv0 = dec[b * D_ + col0],      wc0 = W_c[col0],      vv0 = V[col0];
        float dv1 = dec[b * D_ + col0 + 16], wc1 = W_c[col0 + 16], vv1 = V[col0 + 16];
#pragma unroll
        for (int af = 0; af < 4; ++af) {
            float cov_r[4];
#pragma unroll
            for (int r = 0; r < 4; ++r)
                cov_r[r] = coverage[b * T_ + t0 + af * 16 + rgrp + r];
#pragma unroll
            for (int r = 0; r < 4; ++r) {
                float x0 = acc[af][0][r] + dv0 + cov_r[r] * wc0;
                float x1 = acc[af][1][r] + dv1 + cov_r[r] * wc1;
                p[af][r] += tanh_fast(x0) * vv0 + tanh_fast(x1) * vv1;
            }
        }
    }

    // reduce across the 16 lanes sharing each row (lane bits 0..3)
#pragma unroll
    for (int mm = 1; mm <= 8; mm <<= 1)
#pragma unroll
        for (int af = 0; af < 4; ++af)
#pragma unroll
            for (int r = 0; r < 4; ++r)
                p[af][r] += __shfl_xor(p[af][r], mm, 64);
    if ((l & 15) == 0) {
#pragma unroll
        for (int af = 0; af < 4; ++af)
#pragma unroll
            for (int r = 0; r < 4; ++r)
                red[w][af * 16 + rgrp + r] = p[af][r];
    }
    __syncthreads();
    if (tid < 64) {
        float e = 0.f;
#pragma unroll
        for (int ww = 0; ww < 16; ++ww) e += red[ww][tid];
        e_out[b * T_ + t0 + tid] = e;
        wexp[tid] = __expf(e);
    }
    __syncthreads();

    // ---- fused context partial from the bf16 panel. Wave w handles kt = w.
    // Lane l reads its own frag slot (conflict-free, same algebra as compute).
    {
        float pc[8] = {0, 0, 0, 0, 0, 0, 0, 0};
        const int sl = (slotR ^ (w & 1)) << 4;
#pragma unroll
        for (int af = 0; af < 4; ++af) {
            float wv = wexp[af * 16 + (l & 15)];
            uint4 araw = *(const uint4*)(As + ((af * 16 + w) << 10) + sl);
            const unsigned* u = (const unsigned*)&araw;
#pragma unroll
            for (int q = 0; q < 4; ++q) {
                float f0 = __uint_as_float(u[q] << 16);
                float f1 = __uint_as_float(u[q] & 0xffff0000u);
                pc[2 * q]     = fmaf(wv, f0, pc[2 * q]);
                pc[2 * q + 1] = fmaf(wv, f1, pc[2 * q + 1]);
            }
        }
#pragma unroll
        for (int mm = 1; mm <= 8; mm <<= 1)
#pragma unroll
            for (int j = 0; j < 8; ++j)
                pc[j] += __shfl_xor(pc[j], mm, 64);
        if ((l & 15) == 0) {
            float* dst = part + (size_t)blockIdx.x * D_ + w * 32 + (l >> 4) * 8;
            *(float4*)dst       = float4{pc[0], pc[1], pc[2], pc[3]};
            *(float4*)(dst + 4) = float4{pc[4], pc[5], pc[6], pc[7]};
        }
    }
}

// ---------------------------------------------------------------------------
__global__ __launch_bounds__(256) void k_soft(const float* __restrict__ e_in,
                                              const float* __restrict__ coverage,
                                              float* __restrict__ out_at,
                                              float* __restrict__ out_cov,
                                              float* __restrict__ Sb) {
    int b = blockIdx.x, tid = threadIdx.x;
    __shared__ float red[4];
    float v[16];
    float m = -1e30f;
#pragma unroll
    for (int i = 0; i < 16; ++i) {
        v[i] = e_in[b * T_ + tid + i * 256];
        m = fmaxf(m, v[i]);
    }
#pragma unroll
    for (int mk = 1; mk <= 32; mk <<= 1) m = fmaxf(m, __shfl_xor(m, mk, 64));
    if ((tid & 63) == 0) red[tid >> 6] = m;
    __syncthreads();
    m = fmaxf(fmaxf(red[0], red[1]), fmaxf(red[2], red[3]));
    float s = 0.f;
#pragma unroll
    for (int i = 0; i < 16; ++i) { v[i] = expf(v[i] - m); s += v[i]; }
#pragma unroll
    for (int mk = 1; mk <= 32; mk <<= 1) s += __shfl_xor(s, mk, 64);
    __syncthreads();
    if ((tid & 63) == 0) red[tid >> 6] = s;
    __syncthreads();
    s = red[0] + red[1] + red[2] + red[3];
    if (tid == 0) Sb[b] = __expf(m) * s;
    float inv = 1.0f / s;
#pragma unroll
    for (int i = 0; i < 16; ++i) {
        int idx = b * T_ + tid + i * 256;
        float a = v[i] * inv;
        out_at[idx]  = a;
        out_cov[idx] = coverage[idx] + a;
    }
}

// ---------------------------------------------------------------------------
__global__ __launch_bounds__(256) void k_comb(const float* __restrict__ part,
                                              const float* __restrict__ Sb,
                                              float* __restrict__ out_ctx) {
    int idx = blockIdx.x * 256 + threadIdx.x;
    int b = idx >> 9, d = idx & 511;
    const float* pp = part + (size_t)b * 64 * D_ + d;
    float s = 0.f;
#pragma unroll 8
    for (int j = 0; j < 64; ++j) s += pp[(size_t)j * D_];
    out_ctx[idx] = s / Sb[b];
}

// ---------------------------------------------------------------------------
extern "C" void kernel_launch(void* const* d_in, const int* in_sizes, int n_in,
                              void* d_out, int out_size, void* d_ws, size_t ws_size,
                              hipStream_t stream) {
    const float* h_i      = (const float*)d_in[0];
    const float* s_t      = (const float*)d_in[1];
    const float* coverage = (const float*)d_in[2];
    const float* W_h      = (const float*)d_in[3];
    const float* W_s      = (const float*)d_in[4];
    const float* b_s      = (const float*)d_in[5];
    const float* W_c      = (const float*)d_in[6];
    const float* V        = (const float*)d_in[7];

    float* out_ctx = (float*)d_out;             // B*D
    float* out_at  = out_ctx + B_ * D_;         // B*T (e_t between k_main and k_soft)
    float* out_cov = out_at + BT_;              // B*T

    unsigned short* wsb = (unsigned short*)d_ws;              // 512 KB bf16 W_h frags
    float* dec  = (float*)((char*)d_ws + 524288);             // 64 KB
    float* part = dec + B_ * D_;                              // 4 MB (2048 x 512)
    float* Sb   = part + (size_t)BT_ / 64 * D_;               // 32 floats

    k_conv_wh<<<128, 256, 0, stream>>>(W_h, wsb);
    k_dec<<<B_, 256, 0, stream>>>(s_t, W_s, b_s, dec);
    k_main<<<BT_ / 64, 1024, 0, stream>>>(h_i, coverage, wsb, dec, W_c, V, out_at, part);
    k_soft<<<B_, 256, 0, stream>>>(out_at, coverage, out_at, out_cov, Sb);
    k_comb<<<B_ * D_ / 256, 256, 0, stream>>>(part, Sb, out_ctx);
}

// Round 11
// 182.984 us; speedup vs baseline: 1.7076x; 1.1621x over previous
//
#include <hip/hip_runtime.h>
#include <stdint.h>

#define B_ 32
#define T_ 4096
#define D_ 512
#define BT_ (B_*T_)
#define ROWS_ 32          // rows per block
#define NBLK_ (BT_/ROWS_) // 4096

typedef __attribute__((ext_vector_type(8))) short bf16x8;
typedef __attribute__((ext_vector_type(4))) float f32x4;

__device__ __forceinline__ unsigned short f2bf(float f) {
    unsigned int u = __float_as_uint(f);
    u += 0x7FFFu + ((u >> 16) & 1u);   // round-to-nearest-even (inputs are finite)
    return (unsigned short)(u >> 16);
}

__device__ __forceinline__ unsigned pk2(float a, float b) {
    return (unsigned)f2bf(a) | ((unsigned)f2bf(b) << 16);   // low16 = a, high16 = b
}

__device__ __forceinline__ float bf2f(unsigned short u) {
    return __uint_as_float(((unsigned)u) << 16);
}

__device__ __forceinline__ float tanh_fast(float x) {
    float e2 = __expf(2.0f * x);
    return 1.0f - 2.0f / (e2 + 1.0f);
}

// ---------------------------------------------------------------------------
// W_h (D x D fp32, [k][n]) -> bf16 MFMA B-fragment layout in ws (unchanged).
__global__ __launch_bounds__(256) void k_conv_wh(const float* __restrict__ W_h,
                                                 unsigned short* __restrict__ wsb) {
    int tid = blockIdx.x * 256 + threadIdx.x;
    int l  = tid & 63;
    int kt = (tid >> 6) & 15;
    int nt = tid >> 10;
    int n  = nt * 16 + (l & 15);
    int k0 = kt * 32 + (l >> 4) * 8;
    unsigned int w[4];
#pragma unroll
    for (int q = 0; q < 4; ++q) {
        unsigned short lo = f2bf(W_h[(size_t)(k0 + 2*q)     * D_ + n]);
        unsigned short hi = f2bf(W_h[(size_t)(k0 + 2*q + 1) * D_ + n]);
        w[q] = (unsigned int)lo | ((unsigned int)hi << 16);
    }
    uint4 pk = {w[0], w[1], w[2], w[3]};
    ((uint4*)wsb)[tid] = pk;
}

// ---------------------------------------------------------------------------
__global__ __launch_bounds__(256) void k_dec(const float* __restrict__ s_t,
                                             const float* __restrict__ W_s,
                                             const float* __restrict__ b_s,
                                             float* __restrict__ dec) {
    int b = blockIdx.x;
    int c = threadIdx.x;
    float a0 = b_s[c], a1 = b_s[c + 256];
    const float* srow = s_t + b * D_;
    for (int k = 0; k < D_; ++k) {
        float s = srow[k];
        const float* wr = W_s + (size_t)k * D_;
        a0 = fmaf(s, wr[c], a0);
        a1 = fmaf(s, wr[c + 256], a1);
    }
    dec[b * D_ + c] = a0;
    dec[b * D_ + c + 256] = a1;
}

// ---------------------------------------------------------------------------
// Main fused kernel. Block = 32 rows of (B*T), 16 waves (1024 threads),
// launch_bounds(1024,8) -> 64-reg unified budget, 2 blocks/CU, 8 waves/SIMD.
// Per-wave acc = 2 af x 2 nt x f32x4 = 16 AGPR (the R10 spill fix).
// bf16 panel (32 rows x 512 K = 32KB LDS), sigma-swizzled frag layout,
// convert-on-write. Wave w computes cols [w*32, w*32+32).
// Epilogue fuses tanh/V-dot; context partial (bf16) from the panel, kt = w.
__global__ __launch_bounds__(1024, 8) void k_main(const float* __restrict__ h_i,
                                                  const float* __restrict__ coverage,
                                                  const unsigned short* __restrict__ wsb,
                                                  const float* __restrict__ dec,
                                                  const float* __restrict__ W_c,
                                                  const float* __restrict__ V,
                                                  float* __restrict__ e_out,
                                                  unsigned short* __restrict__ part) {
    __shared__ __align__(16) unsigned char As[32768];   // 32 frags x 1KB
    __shared__ float red[16][ROWS_];
    __shared__ float wexp[ROWS_];
    const int tid = threadIdx.x;
    const int w = tid >> 6, l = tid & 63;      // w: 0..15
    const int row0 = blockIdx.x * ROWS_;
    const int b    = row0 >> 12;
    const int t0   = row0 & (T_ - 1);

    // ---- stage A: pass p: wave w stages row w+16p, lane l chunk c=l (8 floats)
    // frag f = (row>>4)*16 + (l>>2); slot = sigma(lamf, kt), lamf = (row&15)+16*(l&3)
    {
        const int kt_s = l >> 2;
        const int lamf = ((l & 3) << 4) + w;           // row&15 == w (w<=15)
        const int slot = (lamf & 0x38) | ((lamf & 7) ^ ((l & 3) << 1) ^ (kt_s & 1));
        const int sb0  = (kt_s << 10) + (slot << 4);
        const float* gsrc = h_i + (size_t)(row0 + w) * D_ + l * 8;
#pragma unroll
        for (int p = 0; p < 2; ++p) {
            const float* src = gsrc + (size_t)(16 * p) * D_;
            float4 f0 = *(const float4*)src;
            float4 f1 = *(const float4*)(src + 4);
            uint4 pk;
            pk.x = pk2(f0.x, f0.y);
            pk.y = pk2(f0.z, f0.w);
            pk.z = pk2(f1.x, f1.y);
            pk.w = pk2(f1.z, f1.w);
            *(uint4*)(As + (p << 14) + sb0) = pk;      // af = p -> frag base p*16KB
        }
    }
    __syncthreads();

    // ---- K loop: wave w, cols nt = w*2 + {0,1}; 2-deep B prefetch
    const int slotR = (l & 0x38) | ((l & 7) ^ (((l >> 4) & 3) << 1));
    const uint4* bw = (const uint4*)wsb + ((w * 2) << 10) + l;

    f32x4 acc[2][2];
#pragma unroll
    for (int af = 0; af < 2; ++af) {
        acc[af][0] = (f32x4){0, 0, 0, 0};
        acc[af][1] = (f32x4){0, 0, 0, 0};
    }
    uint4 bp[2][2];
    bp[0][0] = bw[0];        bp[0][1] = bw[1 << 10];
    bp[1][0] = bw[1 << 6];   bp[1][1] = bw[(1 << 10) + (1 << 6)];

#pragma unroll
    for (int kt = 0; kt < 16; ++kt) {
        const int sl = (slotR ^ (kt & 1)) << 4;
#pragma unroll
        for (int af = 0; af < 2; ++af) {
            uint4 araw = *(const uint4*)(As + ((af * 16 + kt) << 10) + sl);
            bf16x8 a = __builtin_bit_cast(bf16x8, araw);
            acc[af][0] = __builtin_amdgcn_mfma_f32_16x16x32_bf16(
                a, __builtin_bit_cast(bf16x8, bp[kt & 1][0]), acc[af][0], 0, 0, 0);
            acc[af][1] = __builtin_amdgcn_mfma_f32_16x16x32_bf16(
                a, __builtin_bit_cast(bf16x8, bp[kt & 1][1]), acc[af][1], 0, 0, 0);
        }
        if (kt < 14) {
            bp[kt & 1][0] = bw[((kt + 2) << 6)];
            bp[kt & 1][1] = bw[(1 << 10) + ((kt + 2) << 6)];
        }
    }

    // ---- epilogue: tanh + dot with V over this wave's 32 cols
    const int rgrp = (l >> 4) * 4;
    float p2[2][4] = {{0,0,0,0},{0,0,0,0}};
    {
        int col0 = w * 32 + (l & 15);
        float dv0 = dec[b * D_ + col0],      wc0 = W_c[col0],      vv0 = V[col0];
        float dv1 = dec[b * D_ + col0 + 16], wc1 = W_c[col0 + 16], vv1 = V[col0 + 16];
#pragma unroll
        for (int af = 0; af < 2; ++af) {
            float cov_r[4];
#pragma unroll
            for (int r = 0; r < 4; ++r)
                cov_r[r] = coverage[b * T_ + t0 + af * 16 + rgrp + r];
#pragma unroll
            for (int r = 0; r < 4; ++r) {
                float x0 = acc[af][0][r] + dv0 + cov_r[r] * wc0;
                float x1 = acc[af][1][r] + dv1 + cov_r[r] * wc1;
                p2[af][r] += tanh_fast(x0) * vv0 + tanh_fast(x1) * vv1;
            }
        }
    }

    // reduce across the 16 lanes sharing each row (lane bits 0..3)
#pragma unroll
    for (int mm = 1; mm <= 8; mm <<= 1)
#pragma unroll
        for (int af = 0; af < 2; ++af)
#pragma unroll
            for (int r = 0; r < 4; ++r)
                p2[af][r] += __shfl_xor(p2[af][r], mm, 64);
    if ((l & 15) == 0) {
#pragma unroll
        for (int af = 0; af < 2; ++af)
#pragma unroll
            for (int r = 0; r < 4; ++r)
                red[w][af * 16 + rgrp + r] = p2[af][r];
    }
    __syncthreads();
    if (tid < ROWS_) {
        float e = 0.f;
#pragma unroll
        for (int ww = 0; ww < 16; ++ww) e += red[ww][tid];
        e_out[b * T_ + t0 + tid] = e;
        wexp[tid] = __expf(e);
    }
    __syncthreads();

    // ---- fused context partial (bf16) from the panel. Wave w: kt = w.
    {
        float pc[8] = {0, 0, 0, 0, 0, 0, 0, 0};
        const int sl = (slotR ^ (w & 1)) << 4;
#pragma unroll
        for (int af = 0; af < 2; ++af) {
            float wv = wexp[af * 16 + (l & 15)];
            uint4 araw = *(const uint4*)(As + ((af * 16 + w) << 10) + sl);
            const unsigned* u = (const unsigned*)&araw;
#pragma unroll
            for (int q = 0; q < 4; ++q) {
                float f0 = __uint_as_float(u[q] << 16);
                float f1 = __uint_as_float(u[q] & 0xffff0000u);
                pc[2 * q]     = fmaf(wv, f0, pc[2 * q]);
                pc[2 * q + 1] = fmaf(wv, f1, pc[2 * q + 1]);
            }
        }
#pragma unroll
        for (int mm = 1; mm <= 8; mm <<= 1)
#pragma unroll
            for (int j = 0; j < 8; ++j)
                pc[j] += __shfl_xor(pc[j], mm, 64);
        if ((l & 15) == 0) {
            unsigned short* dst = part + (size_t)blockIdx.x * D_ + w * 32 + (l >> 4) * 8;
            unsigned* d32 = (unsigned*)dst;
            d32[0] = pk2(pc[0], pc[1]);
            d32[1] = pk2(pc[2], pc[3]);
            d32[2] = pk2(pc[4], pc[5]);
            d32[3] = pk2(pc[6], pc[7]);
        }
    }
}

// ---------------------------------------------------------------------------
__global__ __launch_bounds__(256) void k_soft(const float* __restrict__ e_in,
                                              const float* __restrict__ coverage,
                                              float* __restrict__ out_at,
                                              float* __restrict__ out_cov,
                                              float* __restrict__ Sb) {
    int b = blockIdx.x, tid = threadIdx.x;
    __shared__ float red[4];
    float v[16];
    float m = -1e30f;
#pragma unroll
    for (int i = 0; i < 16; ++i) {
        v[i] = e_in[b * T_ + tid + i * 256];
        m = fmaxf(m, v[i]);
    }
#pragma unroll
    for (int mk = 1; mk <= 32; mk <<= 1) m = fmaxf(m, __shfl_xor(m, mk, 64));
    if ((tid & 63) == 0) red[tid >> 6] = m;
    __syncthreads();
    m = fmaxf(fmaxf(red[0], red[1]), fmaxf(red[2], red[3]));
    float s = 0.f;
#pragma unroll
    for (int i = 0; i < 16; ++i) { v[i] = expf(v[i] - m); s += v[i]; }
#pragma unroll
    for (int mk = 1; mk <= 32; mk <<= 1) s += __shfl_xor(s, mk, 64);
    __syncthreads();
    if ((tid & 63) == 0) red[tid >> 6] = s;
    __syncthreads();
    s = red[0] + red[1] + red[2] + red[3];
    if (tid == 0) Sb[b] = __expf(m) * s;
    float inv = 1.0f / s;
#pragma unroll
    for (int i = 0; i < 16; ++i) {
        int idx = b * T_ + tid + i * 256;
        float a = v[i] * inv;
        out_at[idx]  = a;
        out_cov[idx] = coverage[idx] + a;
    }
}

// ---------------------------------------------------------------------------
// combine: context[b][d] = (sum_s part_bf16[(b*128+s)][d]) / S_b  (deterministic)
__global__ __launch_bounds__(256) void k_comb(const unsigned short* __restrict__ part,
                                              const float* __restrict__ Sb,
                                              float* __restrict__ out_ctx) {
    int idx = blockIdx.x * 256 + threadIdx.x;
    int b = idx >> 9, d = idx & 511;
    const unsigned short* pp = part + (size_t)b * 128 * D_ + d;
    float s = 0.f;
#pragma unroll 8
    for (int j = 0; j < 128; ++j) s += bf2f(pp[(size_t)j * D_]);
    out_ctx[idx] = s / Sb[b];
}

// ---------------------------------------------------------------------------
extern "C" void kernel_launch(void* const* d_in, const int* in_sizes, int n_in,
                              void* d_out, int out_size, void* d_ws, size_t ws_size,
                              hipStream_t stream) {
    const float* h_i      = (const float*)d_in[0];
    const float* s_t      = (const float*)d_in[1];
    const float* coverage = (const float*)d_in[2];
    const float* W_h      = (const float*)d_in[3];
    const float* W_s      = (const float*)d_in[4];
    const float* b_s      = (const float*)d_in[5];
    const float* W_c      = (const float*)d_in[6];
    const float* V        = (const float*)d_in[7];

    float* out_ctx = (float*)d_out;             // B*D
    float* out_at  = out_ctx + B_ * D_;         // B*T (e_t between k_main and k_soft)
    float* out_cov = out_at + BT_;              // B*T

    unsigned short* wsb = (unsigned short*)d_ws;              // 512 KB bf16 W_h frags
    float* dec  = (float*)((char*)d_ws + 524288);             // 64 KB
    unsigned short* part = (unsigned short*)(dec + B_ * D_);  // 4 MB (4096 x 512 bf16)
    float* Sb   = (float*)(part + (size_t)NBLK_ * D_);        // 32 floats

    k_conv_wh<<<128, 256, 0, stream>>>(W_h, wsb);
    k_dec<<<B_, 256, 0, stream>>>(s_t, W_s, b_s, dec);
    k_main<<<NBLK_, 1024, 0, stream>>>(h_i, coverage, wsb, dec, W_c, V, out_at, part);
    k_soft<<<B_, 256, 0, stream>>>(out_at, coverage, out_at, out_cov, Sb);
    k_comb<<<B_ * D_ / 256, 256, 0, stream>>>(part, Sb, out_ctx);
}

// Round 12
// 161.612 us; speedup vs baseline: 1.9335x; 1.1322x over previous
//
#include <hip/hip_runtime.h>
#include <stdint.h>

#define B_ 32
#define T_ 4096
#define D_ 512
#define BT_ (B_*T_)
#define ROWS_ 64          // rows per block
#define NBLK_ (BT_/ROWS_) // 2048

typedef __attribute__((ext_vector_type(8))) short bf16x8;
typedef __attribute__((ext_vector_type(4))) float f32x4;

__device__ __forceinline__ unsigned short f2bf(float f) {
    unsigned int u = __float_as_uint(f);
    u += 0x7FFFu + ((u >> 16) & 1u);   // round-to-nearest-even (inputs are finite)
    return (unsigned short)(u >> 16);
}

__device__ __forceinline__ unsigned pk2(float a, float b) {
    return (unsigned)f2bf(a) | ((unsigned)f2bf(b) << 16);   // low16 = a, high16 = b
}

__device__ __forceinline__ float bf2f(unsigned short u) {
    return __uint_as_float(((unsigned)u) << 16);
}

__device__ __forceinline__ float tanh_fast(float x) {
    float e2 = __expf(2.0f * x);
    return 1.0f - 2.0f / (e2 + 1.0f);
}

// ---------------------------------------------------------------------------
// W_h (D x D fp32, [k][n]) -> bf16 MFMA B-fragment layout in ws (unchanged).
__global__ __launch_bounds__(256) void k_conv_wh(const float* __restrict__ W_h,
                                                 unsigned short* __restrict__ wsb) {
    int tid = blockIdx.x * 256 + threadIdx.x;
    int l  = tid & 63;
    int kt = (tid >> 6) & 15;
    int nt = tid >> 10;
    int n  = nt * 16 + (l & 15);
    int k0 = kt * 32 + (l >> 4) * 8;
    unsigned int w[4];
#pragma unroll
    for (int q = 0; q < 4; ++q) {
        unsigned short lo = f2bf(W_h[(size_t)(k0 + 2*q)     * D_ + n]);
        unsigned short hi = f2bf(W_h[(size_t)(k0 + 2*q + 1) * D_ + n]);
        w[q] = (unsigned int)lo | ((unsigned int)hi << 16);
    }
    uint4 pk = {w[0], w[1], w[2], w[3]};
    ((uint4*)wsb)[tid] = pk;
}

// ---------------------------------------------------------------------------
__global__ __launch_bounds__(256) void k_dec(const float* __restrict__ s_t,
                                             const float* __restrict__ W_s,
                                             const float* __restrict__ b_s,
                                             float* __restrict__ dec) {
    int b = blockIdx.x;
    int c = threadIdx.x;
    float a0 = b_s[c], a1 = b_s[c + 256];
    const float* srow = s_t + b * D_;
    for (int k = 0; k < D_; ++k) {
        float s = srow[k];
        const float* wr = W_s + (size_t)k * D_;
        a0 = fmaf(s, wr[c], a0);
        a1 = fmaf(s, wr[c + 256], a1);
    }
    dec[b * D_ + c] = a0;
    dec[b * D_ + c + 256] = a1;
}

// ---------------------------------------------------------------------------
// Main fused kernel. Block = 64 rows of (B*T), 16 waves (1024 threads),
// launch_bounds(1024,8) -> 64-reg unified budget, 2 blocks/CU, 8 waves/SIMD.
// acc[4][2] = 32 AGPR; NO explicit prefetch arrays (R10's spill source) --
// B loads issue directly in the unrolled K-loop, TLP (8 waves/SIMD) hides L2.
// bf16 panel (64 rows x 512 K = 64KB LDS), sigma-swizzled, convert-on-write.
// Wave w computes cols [w*32, w*32+32). Halves per-block B L2 traffic vs R11.
__global__ __launch_bounds__(1024, 8) void k_main(const float* __restrict__ h_i,
                                                  const float* __restrict__ coverage,
                                                  const unsigned short* __restrict__ wsb,
                                                  const float* __restrict__ dec,
                                                  const float* __restrict__ W_c,
                                                  const float* __restrict__ V,
                                                  float* __restrict__ e_out,
                                                  unsigned short* __restrict__ part) {
    __shared__ __align__(16) unsigned char As[65536];   // 64 frags x 1KB
    __shared__ float red[16][ROWS_];
    __shared__ float wexp[ROWS_];
    const int tid = threadIdx.x;
    const int w = tid >> 6, l = tid & 63;      // w: 0..15
    const int row0 = blockIdx.x * ROWS_;
    const int b    = row0 >> 12;
    const int t0   = row0 & (T_ - 1);

    // ---- stage A: pass p in 0..3: wave w stages row w+16p, lane l chunk l.
    // frag f = p*16 + (l>>2); slot = sigma(lamf, kt_s), lamf = w + 16*(l&3).
    {
        const int kt_s = l >> 2;
        const int lamf = ((l & 3) << 4) + w;           // row&15 == w
        const int slot = (lamf & 0x38) | ((lamf & 7) ^ ((l & 3) << 1) ^ (kt_s & 1));
        const int sb0  = (kt_s << 10) + (slot << 4);
        const float* gsrc = h_i + (size_t)(row0 + w) * D_ + l * 8;
#pragma unroll
        for (int p = 0; p < 4; ++p) {
            const float* src = gsrc + (size_t)(16 * p) * D_;
            float4 f0 = *(const float4*)src;
            float4 f1 = *(const float4*)(src + 4);
            uint4 pk;
            pk.x = pk2(f0.x, f0.y);
            pk.y = pk2(f0.z, f0.w);
            pk.z = pk2(f1.x, f1.y);
            pk.w = pk2(f1.z, f1.w);
            *(uint4*)(As + (p << 14) + sb0) = pk;      // af = p
        }
    }
    __syncthreads();

    // ---- K loop: wave w, cols nt = w*2 + {0,1}; direct B loads (no arrays)
    const int slotR = (l & 0x38) | ((l & 7) ^ (((l >> 4) & 3) << 1));
    const uint4* bw = (const uint4*)wsb + ((w * 2) << 10) + l;

    f32x4 acc[4][2];
#pragma unroll
    for (int af = 0; af < 4; ++af) {
        acc[af][0] = (f32x4){0, 0, 0, 0};
        acc[af][1] = (f32x4){0, 0, 0, 0};
    }

#pragma unroll
    for (int kt = 0; kt < 16; ++kt) {
        const int sl = (slotR ^ (kt & 1)) << 4;
        uint4 b0 = bw[(kt << 6)];
        uint4 b1 = bw[(1 << 10) + (kt << 6)];
#pragma unroll
        for (int af = 0; af < 4; ++af) {
            uint4 araw = *(const uint4*)(As + ((af * 16 + kt) << 10) + sl);
            bf16x8 a = __builtin_bit_cast(bf16x8, araw);
            acc[af][0] = __builtin_amdgcn_mfma_f32_16x16x32_bf16(
                a, __builtin_bit_cast(bf16x8, b0), acc[af][0], 0, 0, 0);
            acc[af][1] = __builtin_amdgcn_mfma_f32_16x16x32_bf16(
                a, __builtin_bit_cast(bf16x8, b1), acc[af][1], 0, 0, 0);
        }
    }

    // ---- epilogue: tanh + dot with V over this wave's 32 cols
    const int rgrp = (l >> 4) * 4;
    float p2[4][4] = {{0,0,0,0},{0,0,0,0},{0,0,0,0},{0,0,0,0}};
    {
        int col0 = w * 32 + (l & 15);
        float dv0 = dec[b * D_ + col0],      wc0 = W_c[col0],      vv0 = V[col0];
        float dv1 = dec[b * D_ + col0 + 16], wc1 = W_c[col0 + 16], vv1 = V[col0 + 16];
#pragma unroll
        for (int af = 0; af < 4; ++af) {
            float cov_r[4];
#pragma unroll
            for (int r = 0; r < 4; ++r)
                cov_r[r] = coverage[b * T_ + t0 + af * 16 + rgrp + r];
#pragma unroll
            for (int r = 0; r < 4; ++r) {
                float x0 = acc[af][0][r] + dv0 + cov_r[r] * wc0;
                float x1 = acc[af][1][r] + dv1 + cov_r[r] * wc1;
                p2[af][r] += tanh_fast(x0) * vv0 + tanh_fast(x1) * vv1;
            }
        }
    }

    // reduce across the 16 lanes sharing each row (lane bits 0..3)
#pragma unroll
    for (int mm = 1; mm <= 8; mm <<= 1)
#pragma unroll
        for (int af = 0; af < 4; ++af)
#pragma unroll
            for (int r = 0; r < 4; ++r)
                p2[af][r] += __shfl_xor(p2[af][r], mm, 64);
    if ((l & 15) == 0) {
#pragma unroll
        for (int af = 0; af < 4; ++af)
#pragma unroll
            for (int r = 0; r < 4; ++r)
                red[w][af * 16 + rgrp + r] = p2[af][r];
    }
    __syncthreads();
    if (tid < ROWS_) {
        float e = 0.f;
#pragma unroll
        for (int ww = 0; ww < 16; ++ww) e += red[ww][tid];
        e_out[b * T_ + t0 + tid] = e;
        wexp[tid] = __expf(e);
    }
    __syncthreads();

    // ---- fused context partial (bf16) from the panel. Wave w: kt = w.
    {
        float pc[8] = {0, 0, 0, 0, 0, 0, 0, 0};
        const int sl = (slotR ^ (w & 1)) << 4;
#pragma unroll
        for (int af = 0; af < 4; ++af) {
            float wv = wexp[af * 16 + (l & 15)];
            uint4 araw = *(const uint4*)(As + ((af * 16 + w) << 10) + sl);
            const unsigned* u = (const unsigned*)&araw;
#pragma unroll
            for (int q = 0; q < 4; ++q) {
                float f0 = __uint_as_float(u[q] << 16);
                float f1 = __uint_as_float(u[q] & 0xffff0000u);
                pc[2 * q]     = fmaf(wv, f0, pc[2 * q]);
                pc[2 * q + 1] = fmaf(wv, f1, pc[2 * q + 1]);
            }
        }
#pragma unroll
        for (int mm = 1; mm <= 8; mm <<= 1)
#pragma unroll
            for (int j = 0; j < 8; ++j)
                pc[j] += __shfl_xor(pc[j], mm, 64);
        if ((l & 15) == 0) {
            unsigned short* dst = part + (size_t)blockIdx.x * D_ + w * 32 + (l >> 4) * 8;
            unsigned* d32 = (unsigned*)dst;
            d32[0] = pk2(pc[0], pc[1]);
            d32[1] = pk2(pc[2], pc[3]);
            d32[2] = pk2(pc[4], pc[5]);
            d32[3] = pk2(pc[6], pc[7]);
        }
    }
}

// ---------------------------------------------------------------------------
__global__ __launch_bounds__(256) void k_soft(const float* __restrict__ e_in,
                                              const float* __restrict__ coverage,
                                              float* __restrict__ out_at,
                                              float* __restrict__ out_cov,
                                              float* __restrict__ Sb) {
    int b = blockIdx.x, tid = threadIdx.x;
    __shared__ float red[4];
    float v[16];
    float m = -1e30f;
#pragma unroll
    for (int i = 0; i < 16; ++i) {
        v[i] = e_in[b * T_ + tid + i * 256];
        m = fmaxf(m, v[i]);
    }
#pragma unroll
    for (int mk = 1; mk <= 32; mk <<= 1) m = fmaxf(m, __shfl_xor(m, mk, 64));
    if ((tid & 63) == 0) red[tid >> 6] = m;
    __syncthreads();
    m = fmaxf(fmaxf(red[0], red[1]), fmaxf(red[2], red[3]));
    float s = 0.f;
#pragma unroll
    for (int i = 0; i < 16; ++i) { v[i] = expf(v[i] - m); s += v[i]; }
#pragma unroll
    for (int mk = 1; mk <= 32; mk <<= 1) s += __shfl_xor(s, mk, 64);
    __syncthreads();
    if ((tid & 63) == 0) red[tid >> 6] = s;
    __syncthreads();
    s = red[0] + red[1] + red[2] + red[3];
    if (tid == 0) Sb[b] = __expf(m) * s;
    float inv = 1.0f / s;
#pragma unroll
    for (int i = 0; i < 16; ++i) {
        int idx = b * T_ + tid + i * 256;
        float a = v[i] * inv;
        out_at[idx]  = a;
        out_cov[idx] = coverage[idx] + a;
    }
}

// ---------------------------------------------------------------------------
// combine: context[b][d] = (sum_s part_bf16[(b*64+s)][d]) / S_b  (deterministic)
__global__ __launch_bounds__(256) void k_comb(const unsigned short* __restrict__ part,
                                              const float* __restrict__ Sb,
                                              float* __restrict__ out_ctx) {
    int idx = blockIdx.x * 256 + threadIdx.x;
    int b = idx >> 9, d = idx & 511;
    const unsigned short* pp = part + (size_t)b * 64 * D_ + d;
    float s = 0.f;
#pragma unroll 8
    for (int j = 0; j < 64; ++j) s += bf2f(pp[(size_t)j * D_]);
    out_ctx[idx] = s / Sb[b];
}

// ---------------------------------------------------------------------------
extern "C" void kernel_launch(void* const* d_in, const int* in_sizes, int n_in,
                              void* d_out, int out_size, void* d_ws, size_t ws_size,
                              hipStream_t stream) {
    const float* h_i      = (const float*)d_in[0];
    const float* s_t      = (const float*)d_in[1];
    const float* coverage = (const float*)d_in[2];
    const float* W_h      = (const float*)d_in[3];
    const float* W_s      = (const float*)d_in[4];
    const float* b_s      = (const float*)d_in[5];
    const float* W_c      = (const float*)d_in[6];
    const float* V        = (const float*)d_in[7];

    float* out_ctx = (float*)d_out;             // B*D
    float* out_at  = out_ctx + B_ * D_;         // B*T (e_t between k_main and k_soft)
    float* out_cov = out_at + BT_;              // B*T

    unsigned short* wsb = (unsigned short*)d_ws;              // 512 KB bf16 W_h frags
    float* dec  = (float*)((char*)d_ws + 524288);             // 64 KB
    unsigned short* part = (unsigned short*)(dec + B_ * D_);  // 2 MB (2048 x 512 bf16)
    float* Sb   = (float*)(part + (size_t)NBLK_ * D_);        // 32 floats

    k_conv_wh<<<128, 256, 0, stream>>>(W_h, wsb);
    k_dec<<<B_, 256, 0, stream>>>(s_t, W_s, b_s, dec);
    k_main<<<NBLK_, 1024, 0, stream>>>(h_i, coverage, wsb, dec, W_c, V, out_at, part);
    k_soft<<<B_, 256, 0, stream>>>(out_at, coverage, out_at, out_cov, Sb);
    k_comb<<<B_ * D_ / 256, 256, 0, stream>>>(part, Sb, out_ctx);
}